// Round 11
// baseline (144.851 us; speedup 1.0000x reference)
//
#include <hip/hip_runtime.h>
#include <hip/hip_bf16.h>
#include <stdint.h>

// B,C,H,W = 2,64,96,96. Inputs fp32, output fp32.
// proj3: QKV 1x1 convs -> bf16 q(*log2e), k, V key-PERMUTED channel-major.
// attn5: zero-LDS-loop flash attention, 64q/wave, K+V double-buffer
//        prefetch, softmax denominator via ones-row MFMA. (r9-verified code.)
// combine: sum G key-split partials, normalize, + gamma*attn + x.
#define BB 2
#define CC 64
#define PP 9216
#define QTILES 144               // PP/64
#define LOG2E 1.4426950408889634f

typedef unsigned short ushort;
typedef __attribute__((ext_vector_type(8))) short short8;
typedef __attribute__((ext_vector_type(4))) float floatx4;
typedef __attribute__((ext_vector_type(4))) int intx4;

#if defined(__has_builtin)
#if __has_builtin(__builtin_amdgcn_exp2f)
#define EXP2(x) __builtin_amdgcn_exp2f(x)
#endif
#endif
#ifndef EXP2
#define EXP2(x) exp2f(x)
#endif

__device__ __forceinline__ ushort f2bf(float f) {
    unsigned int u = __float_as_uint(f);
    u = (u + 0x7fffu + ((u >> 16) & 1u)) >> 16;   // RNE
    return (ushort)u;
}

__device__ __forceinline__ unsigned int pack_bf2(float w0, float w1) {
    // bf16 pair (round-half-up), packed with one v_perm_b32
    unsigned int u0 = __float_as_uint(w0) + 0x8000u;
    unsigned int u1 = __float_as_uint(w1) + 0x8000u;
#if defined(__has_builtin) && __has_builtin(__builtin_amdgcn_perm)
    return __builtin_amdgcn_perm(u1, u0, 0x07060302u);
#else
    return (u1 & 0xffff0000u) | (u0 >> 16);
#endif
}

// ---------------------------------------------------------------------------
// Kernel 1: QKV projection. 576 blocks x 256 (4 waves; wave = 64 px x 10 rows;
// 2 blocks per 64-px tile, each covering 40 of the 80 output rows).
// Rows 0-7: q (scaled by LOG2E), 8-15: k, 16-79: v.
// V keys permuted within 32-groups: slot = ((k>>2)&3)*8 + ((k>>4)&1)*4 + (k&3)
// so PV's B-operand slot k'=quad*8+j matches QK's D[key][q] output rows.
// ---------------------------------------------------------------------------
__global__ __launch_bounds__(256)
void proj3(const float* __restrict__ x,
           const float* __restrict__ Wq, const float* __restrict__ bq,
           const float* __restrict__ Wk, const float* __restrict__ bk,
           const float* __restrict__ Wv, const float* __restrict__ bv,
           ushort* __restrict__ qbuf, ushort* __restrict__ kbuf,
           ushort* __restrict__ vfw)
{
    const int tid = threadIdx.x;
    const int px  = tid & 63;
    const int og  = __builtin_amdgcn_readfirstlane(tid >> 6);  // 0..3, wave-uniform
    const int blk = blockIdx.x;
    const int b     = blk / (2 * QTILES);
    const int rem   = blk % (2 * QTILES);
    const int ptile = rem >> 1;
    const int rhalf = rem & 1;
    const int p     = ptile * 64 + px;
    const int r0    = rhalf * 40 + og * 10;      // first of this thread's 10 rows

    const float* wr[10];
#pragma unroll
    for (int r = 0; r < 10; ++r) {
        const int row = r0 + r;
        wr[r] = (row < 8) ? (Wq + row * 64)
              : (row < 16) ? (Wk + (row - 8) * 64)
              : (Wv + (row - 16) * 64);
    }

    float xv[64];
#pragma unroll
    for (int c = 0; c < 64; ++c)
        xv[c] = x[((size_t)b * 64 + c) * PP + p];

    float acc[10];
#pragma unroll
    for (int r = 0; r < 10; ++r) acc[r] = 0.f;
#pragma unroll
    for (int c = 0; c < 64; ++c) {
#pragma unroll
        for (int r = 0; r < 10; ++r)
            acc[r] = fmaf(wr[r][c], xv[c], acc[r]);
    }

#pragma unroll
    for (int r = 0; r < 10; ++r) {
        const int row = r0 + r;
        if (row < 8) {
            const float v = (acc[r] + bq[row]) * LOG2E;
            qbuf[((size_t)b * PP + p) * 8 + row] = f2bf(v);
        } else if (row < 16) {
            const float v = acc[r] + bk[row - 8];
            kbuf[((size_t)b * PP + p) * 8 + (row - 8)] = f2bf(v);
        } else {
            const int co = row - 16;
            const float v = acc[r] + bv[co];
            const int pl = p & 31;     // slot permutation within 32-group
            const int ps = (p & ~31) | ((((pl >> 2) & 3) << 3) | (((pl >> 4) & 1) << 2) | (pl & 3));
            vfw[((size_t)b * 64 + co) * PP + ps] = f2bf(v);
        }
    }
}

// ---------------------------------------------------------------------------
// Kernel 2: zero-LDS-loop MFMA flash attention, 64q/wave, K+V prefetch.
// Grid = G*BB*QTILES blocks of 128 (2 waves; wave = 64 q x 32 keys/64-tile).
// QK: E = mfma(A=K, B=Q) -> D[key][q]; K quads 1-3 load garbage (Q k-slots
// >=8 zeroed -> contributes exactly 0). P packed in regs as PV B-operand
// (V key-permuted). lsum via ones-row MFMA. Next-tile loads issued before
// current-tile use.
// ---------------------------------------------------------------------------
__global__ __launch_bounds__(128, 3)
void attn5(const ushort* __restrict__ qbuf, const ushort* __restrict__ kbuf,
           const ushort* __restrict__ vfw,
           ushort* __restrict__ accp, float* __restrict__ lsump,
           int keysPerG, int numTiles)
{
    __shared__ __align__(16) float smerge[64 * 64];  // 16 KB epilogue merge
    __shared__ float slsum[64];

    const int tid  = threadIdx.x;
    const int lane = tid & 63;
    const int wid  = tid >> 6;
    const int col  = lane & 15;
    const int quad = lane >> 4;

    const int qt = blockIdx.x % QTILES;
    const int gb = blockIdx.x / QTILES;
    const int b  = gb % BB;
    const int g  = gb / BB;
    const int q0 = qt * 64;

    const short8 zf = {0, 0, 0, 0, 0, 0, 0, 0};
    const short vone = (short)0x3F80;                 // bf16 1.0
    const short8 vones = {vone, vone, vone, vone, vone, vone, vone, vone};

    // Q fragments (B-operand: B[k=d=quad*8+j][n=q=col]); only quad 0 real.
    short8 qfragB[4];
#pragma unroll
    for (int qh = 0; qh < 4; ++qh)
        qfragB[qh] = (quad == 0)
            ? *(const short8*)(qbuf + ((size_t)b * PP + q0 + qh * 16 + col) * 8)
            : zf;

    floatx4 acc[4][4];
#pragma unroll
    for (int qh = 0; qh < 4; ++qh)
#pragma unroll
        for (int cb = 0; cb < 4; ++cb) acc[qh][cb] = (floatx4){0.f, 0.f, 0.f, 0.f};
    floatx4 accLh[4];
#pragma unroll
    for (int qh = 0; qh < 4; ++qh) accLh[qh] = (floatx4){0.f, 0.f, 0.f, 0.f};

    const ushort* kB = kbuf + (size_t)b * PP * 8;
    const ushort* vB = vfw + (size_t)b * 64 * PP;
    const int kwbase = g * keysPerG + wid * 32;

    // ---- prefetch tile 0 (K A-operand quads 1-3 garbage-ok; V key-permuted) --
    short8 kf0c = *(const short8*)(kB + (size_t)(kwbase + col) * 8 + quad * 8);
    short8 kf1c = *(const short8*)(kB + (size_t)(kwbase + 16 + col) * 8 + quad * 8);
    short8 vfc[4];
#pragma unroll
    for (int cb = 0; cb < 4; ++cb)
        vfc[cb] = *(const short8*)(vB + ((size_t)(cb * 16 + col)) * PP + kwbase + quad * 8);

    for (int t = 0; t < numTiles; ++t) {
        const int tn  = (t + 1 < numTiles) ? (t + 1) : t;
        const int kwn = kwbase + tn * 64;

        // ---- issue ALL next-tile loads before any current-tile use ----
        const short8 kf0n = *(const short8*)(kB + (size_t)(kwn + col) * 8 + quad * 8);
        const short8 kf1n = *(const short8*)(kB + (size_t)(kwn + 16 + col) * 8 + quad * 8);
        short8 vfn[4];
#pragma unroll
        for (int cb = 0; cb < 4; ++cb)
            vfn[cb] = *(const short8*)(vB + ((size_t)(cb * 16 + col)) * PP + kwn + quad * 8);

        // ---- compute on current-tile fragments ----
#pragma unroll
        for (int qh = 0; qh < 4; ++qh) {
            const floatx4 E0 = __builtin_amdgcn_mfma_f32_16x16x32_bf16(
                kf0c, qfragB[qh], (floatx4){0.f, 0.f, 0.f, 0.f}, 0, 0, 0);
            const floatx4 E1 = __builtin_amdgcn_mfma_f32_16x16x32_bf16(
                kf1c, qfragB[qh], (floatx4){0.f, 0.f, 0.f, 0.f}, 0, 0, 0);

            const float w00 = EXP2(E0[0]), w01 = EXP2(E0[1]);
            const float w02 = EXP2(E0[2]), w03 = EXP2(E0[3]);
            const float w10 = EXP2(E1[0]), w11 = EXP2(E1[1]);
            const float w12 = EXP2(E1[2]), w13 = EXP2(E1[3]);
            intx4 pi;
            pi.x = pack_bf2(w00, w01);   // slots quad*8 + 0,1
            pi.y = pack_bf2(w02, w03);   // slots quad*8 + 2,3
            pi.z = pack_bf2(w10, w11);   // slots quad*8 + 4,5
            pi.w = pack_bf2(w12, w13);   // slots quad*8 + 6,7
            const short8 pf = __builtin_bit_cast(short8, pi);

            accLh[qh] = __builtin_amdgcn_mfma_f32_16x16x32_bf16(vones, pf, accLh[qh], 0, 0, 0);
#pragma unroll
            for (int cb = 0; cb < 4; ++cb)
                acc[qh][cb] = __builtin_amdgcn_mfma_f32_16x16x32_bf16(
                    vfc[cb], pf, acc[qh][cb], 0, 0, 0);
        }

        kf0c = kf0n;
        kf1c = kf1n;
#pragma unroll
        for (int cb = 0; cb < 4; ++cb) vfc[cb] = vfn[cb];
    }

    // ---- merge the two waves' key-halves via LDS; wave 0 stores ----
    if (wid == 1) {
#pragma unroll
        for (int qh = 0; qh < 4; ++qh)
#pragma unroll
            for (int cb = 0; cb < 4; ++cb)
#pragma unroll
                for (int r = 0; r < 4; ++r)
                    smerge[(cb * 16 + quad * 4 + r) * 64 + qh * 16 + col] = acc[qh][cb][r];
        if (quad == 0)
#pragma unroll
            for (int qh = 0; qh < 4; ++qh)
                slsum[qh * 16 + col] = accLh[qh][0];
    }
    __syncthreads();
    if (wid == 0) {
        ushort* ab = accp + ((size_t)g * BB + b) * CC * PP;
#pragma unroll
        for (int qh = 0; qh < 4; ++qh)
#pragma unroll
            for (int cb = 0; cb < 4; ++cb)
#pragma unroll
                for (int r = 0; r < 4; ++r) {
                    const int c = cb * 16 + quad * 4 + r;
                    const float v = acc[qh][cb][r] + smerge[c * 64 + qh * 16 + col];
                    ab[(size_t)c * PP + q0 + qh * 16 + col] = f2bf(v);
                }
        if (quad == 0) {
            float* lb = lsump + ((size_t)g * BB + b) * PP + q0;
#pragma unroll
            for (int qh = 0; qh < 4; ++qh)
                lb[qh * 16 + col] = accLh[qh][0] + slsum[qh * 16 + col];
        }
    }
}

// ---------------------------------------------------------------------------
// Kernel 3: combine G partials, normalize, + gamma*attn + x. 576 x 256,
// 8 consecutive pixels per thread (layouts already [b][c][p]-major).
// ---------------------------------------------------------------------------
__global__ __launch_bounds__(256)
void combine(const ushort* __restrict__ accp, const float* __restrict__ lsump,
             const float* __restrict__ x, const float* __restrict__ gamma,
             float* __restrict__ out, int G)
{
    const size_t i8 = ((size_t)blockIdx.x * 256 + threadIdx.x) * 8;
    const int b = (int)(i8 / ((size_t)CC * PP));
    const int p = (int)(i8 % PP);
    const float gm = gamma[0];

    float asum[8] = {}, lst[8] = {};
    for (int g = 0; g < G; ++g) {
        const uint4 av = *(const uint4*)(accp + (size_t)g * (BB * CC * PP) + i8);
        const unsigned int u[4] = {av.x, av.y, av.z, av.w};
#pragma unroll
        for (int k = 0; k < 4; ++k) {
            asum[2 * k]     += __uint_as_float(u[k] << 16);
            asum[2 * k + 1] += __uint_as_float(u[k] & 0xffff0000u);
        }
        const float* lp = lsump + ((size_t)g * BB + b) * PP + p;
        const float4 l0 = *(const float4*)lp;
        const float4 l1 = *(const float4*)(lp + 4);
        lst[0] += l0.x; lst[1] += l0.y; lst[2] += l0.z; lst[3] += l0.w;
        lst[4] += l1.x; lst[5] += l1.y; lst[6] += l1.z; lst[7] += l1.w;
    }

    const float4 x0 = *(const float4*)(x + i8);
    const float4 x1 = *(const float4*)(x + i8 + 4);
    float o[8] = {x0.x, x0.y, x0.z, x0.w, x1.x, x1.y, x1.z, x1.w};
#pragma unroll
    for (int j = 0; j < 8; ++j)
        o[j] = fmaf(asum[j], gm / fmaxf(lst[j], 1e-30f), o[j]);
    *(float4*)(out + i8)     = make_float4(o[0], o[1], o[2], o[3]);
    *(float4*)(out + i8 + 4) = make_float4(o[4], o[5], o[6], o[7]);
}

// ---------------------------------------------------------------------------
extern "C" void kernel_launch(void* const* d_in, const int* in_sizes, int n_in,
                              void* d_out, int out_size, void* d_ws, size_t ws_size,
                              hipStream_t stream)
{
    const float* x     = (const float*)d_in[0];
    const float* Wq    = (const float*)d_in[1];
    const float* bq    = (const float*)d_in[2];
    const float* Wk    = (const float*)d_in[3];
    const float* bk    = (const float*)d_in[4];
    const float* Wv    = (const float*)d_in[5];
    const float* bv    = (const float*)d_in[6];
    const float* gamma = (const float*)d_in[7];
    float* out = (float*)d_out;

    // ws: qbuf | kbuf | vfw (bf16) | accp (bf16, G slots) | lsump (f32)
    const size_t nQK  = (size_t)BB * PP * 8;        // elems
    const size_t nV   = (size_t)BB * CC * PP;
    const size_t base = 2 * nQK * 2 + nV * 2;       // bytes
    const size_t perG = nV * 2 + (size_t)BB * PP * 4;
    const int G = (ws_size >= base + 16 * perG) ? 16
                : (ws_size >= base + 8 * perG) ? 8
                : (ws_size >= base + 6 * perG) ? 6
                : (ws_size >= base + 4 * perG) ? 4 : 2;
    const int keysPerG = PP / G;
    const int numTiles = keysPerG / 64;

    ushort* qbuf = (ushort*)d_ws;
    ushort* kbuf = qbuf + nQK;
    ushort* vfw  = kbuf + nQK;
    ushort* accp = vfw + nV;
    float* lsump = (float*)(accp + (size_t)G * nV);

    proj3<<<dim3(BB * 2 * QTILES), dim3(256), 0, stream>>>(
        x, Wq, bq, Wk, bk, Wv, bv, qbuf, kbuf, vfw);
    attn5<<<dim3(G * BB * QTILES), dim3(128), 0, stream>>>(
        qbuf, kbuf, vfw, accp, lsump, keysPerG, numTiles);
    combine<<<dim3(576), dim3(256), 0, stream>>>(
        accp, lsump, x, gamma, out, G);
}

// Round 12
// 139.755 us; speedup vs baseline: 1.0365x; 1.0365x over previous
//
#include <hip/hip_runtime.h>
#include <hip/hip_bf16.h>
#include <stdint.h>

// B,C,H,W = 2,64,96,96. Inputs fp32, output fp32.
// proj3: QKV 1x1 convs -> bf16 q(*log2e), k, V key-PERMUTED channel-major.
// attn7: zero-LDS-loop flash attention, 64q/wave, K+V prefetch (r9/r11
//        structure), P computed as bf16 bits via Schraudolph (fma+cvt+or);
//        denominator via ones-row MFMA over the same bf16 P.
// combine: sum G key-split partials, normalize, + gamma*attn + x.
#define BB 2
#define CC 64
#define PP 9216
#define QTILES 144               // PP/64
#define LOG2E 1.4426950408889634f
// Schraudolph magic for bf16 2^E bits: E*128 + (127 - 0.05730496)*128
#define SCH_C 16248.664965f

typedef unsigned short ushort;
typedef __attribute__((ext_vector_type(8))) short short8;
typedef __attribute__((ext_vector_type(4))) float floatx4;
typedef __attribute__((ext_vector_type(4))) int intx4;

__device__ __forceinline__ ushort f2bf(float f) {
    unsigned int u = __float_as_uint(f);
    u = (u + 0x7fffu + ((u >> 16) & 1u)) >> 16;   // RNE
    return (ushort)u;
}

// 2^e0, 2^e1 as packed bf16 pair via Schraudolph (arg always > 0 -> trunc=floor)
__device__ __forceinline__ unsigned int exp2_pk_bf16(float e0, float e1) {
    const int i0 = (int)fmaf(e0, 128.f, SCH_C);
    const int i1 = (int)fmaf(e1, 128.f, SCH_C);
    return (unsigned int)i0 | ((unsigned int)i1 << 16);
}

// ---------------------------------------------------------------------------
// Kernel 1: QKV projection. 576 blocks x 256 (4 waves; wave = 64 px x 10 rows;
// 2 blocks per 64-px tile, each covering 40 of the 80 output rows).
// Rows 0-7: q (scaled by LOG2E), 8-15: k, 16-79: v.
// V keys permuted within 32-groups: slot = ((k>>2)&3)*8 + ((k>>4)&1)*4 + (k&3)
// so PV's B-operand slot k'=quad*8+j matches QK's D[key][q] output rows.
// ---------------------------------------------------------------------------
__global__ __launch_bounds__(256)
void proj3(const float* __restrict__ x,
           const float* __restrict__ Wq, const float* __restrict__ bq,
           const float* __restrict__ Wk, const float* __restrict__ bk,
           const float* __restrict__ Wv, const float* __restrict__ bv,
           ushort* __restrict__ qbuf, ushort* __restrict__ kbuf,
           ushort* __restrict__ vfw)
{
    const int tid = threadIdx.x;
    const int px  = tid & 63;
    const int og  = __builtin_amdgcn_readfirstlane(tid >> 6);  // 0..3, wave-uniform
    const int blk = blockIdx.x;
    const int b     = blk / (2 * QTILES);
    const int rem   = blk % (2 * QTILES);
    const int ptile = rem >> 1;
    const int rhalf = rem & 1;
    const int p     = ptile * 64 + px;
    const int r0    = rhalf * 40 + og * 10;      // first of this thread's 10 rows

    const float* wr[10];
#pragma unroll
    for (int r = 0; r < 10; ++r) {
        const int row = r0 + r;
        wr[r] = (row < 8) ? (Wq + row * 64)
              : (row < 16) ? (Wk + (row - 8) * 64)
              : (Wv + (row - 16) * 64);
    }

    float xv[64];
#pragma unroll
    for (int c = 0; c < 64; ++c)
        xv[c] = x[((size_t)b * 64 + c) * PP + p];

    float acc[10];
#pragma unroll
    for (int r = 0; r < 10; ++r) acc[r] = 0.f;
#pragma unroll
    for (int c = 0; c < 64; ++c) {
#pragma unroll
        for (int r = 0; r < 10; ++r)
            acc[r] = fmaf(wr[r][c], xv[c], acc[r]);
    }

#pragma unroll
    for (int r = 0; r < 10; ++r) {
        const int row = r0 + r;
        if (row < 8) {
            const float v = (acc[r] + bq[row]) * LOG2E;
            qbuf[((size_t)b * PP + p) * 8 + row] = f2bf(v);
        } else if (row < 16) {
            const float v = acc[r] + bk[row - 8];
            kbuf[((size_t)b * PP + p) * 8 + (row - 8)] = f2bf(v);
        } else {
            const int co = row - 16;
            const float v = acc[r] + bv[co];
            const int pl = p & 31;     // slot permutation within 32-group
            const int ps = (p & ~31) | ((((pl >> 2) & 3) << 3) | (((pl >> 4) & 1) << 2) | (pl & 3));
            vfw[((size_t)b * 64 + co) * PP + ps] = f2bf(v);
        }
    }
}

// ---------------------------------------------------------------------------
// Kernel 2: zero-LDS-loop MFMA flash attention, 64q/wave, K+V prefetch,
// Schraudolph bf16 P. Grid = G*BB*QTILES blocks of 128 (2 waves; wave =
// 64 q x 32 keys of each 64-key tile).
// QK: E = mfma(A=K, B=Q) -> D[key][q]; K quads 1-3 load garbage (Q k-slots
// >=8 zeroed -> contributes exactly 0). P packed in regs as PV B-operand
// (V key-permuted). lsum via ones-row MFMA over the same bf16 P. Next-tile
// loads issued before current-tile use. NO unroll pragma on the t-loop.
// ---------------------------------------------------------------------------
__global__ __launch_bounds__(128, 3)
void attn7(const ushort* __restrict__ qbuf, const ushort* __restrict__ kbuf,
           const ushort* __restrict__ vfw,
           ushort* __restrict__ accp, float* __restrict__ lsump,
           int keysPerG, int numTiles)
{
    __shared__ __align__(16) float smerge[64 * 64];  // 16 KB epilogue merge
    __shared__ float slsum[64];

    const int tid  = threadIdx.x;
    const int lane = tid & 63;
    const int wid  = tid >> 6;
    const int col  = lane & 15;
    const int quad = lane >> 4;

    const int qt = blockIdx.x % QTILES;
    const int gb = blockIdx.x / QTILES;
    const int b  = gb % BB;
    const int g  = gb / BB;
    const int q0 = qt * 64;

    const short8 zf = {0, 0, 0, 0, 0, 0, 0, 0};
    const short vone = (short)0x3F80;                 // bf16 1.0
    const short8 vones = {vone, vone, vone, vone, vone, vone, vone, vone};

    // Q fragments (B-operand: B[k=d=quad*8+j][n=q=col]); only quad 0 real.
    short8 qfragB[4];
#pragma unroll
    for (int qh = 0; qh < 4; ++qh)
        qfragB[qh] = (quad == 0)
            ? *(const short8*)(qbuf + ((size_t)b * PP + q0 + qh * 16 + col) * 8)
            : zf;

    floatx4 acc[4][4];
#pragma unroll
    for (int qh = 0; qh < 4; ++qh)
#pragma unroll
        for (int cb = 0; cb < 4; ++cb) acc[qh][cb] = (floatx4){0.f, 0.f, 0.f, 0.f};
    floatx4 accLh[4];
#pragma unroll
    for (int qh = 0; qh < 4; ++qh) accLh[qh] = (floatx4){0.f, 0.f, 0.f, 0.f};

    const ushort* kB = kbuf + (size_t)b * PP * 8;
    const ushort* vB = vfw + (size_t)b * 64 * PP;
    const int kwbase = g * keysPerG + wid * 32;

    // ---- prefetch tile 0 (K A-operand quads 1-3 garbage-ok; V key-permuted) --
    short8 kf0c = *(const short8*)(kB + (size_t)(kwbase + col) * 8 + quad * 8);
    short8 kf1c = *(const short8*)(kB + (size_t)(kwbase + 16 + col) * 8 + quad * 8);
    short8 vfc[4];
#pragma unroll
    for (int cb = 0; cb < 4; ++cb)
        vfc[cb] = *(const short8*)(vB + ((size_t)(cb * 16 + col)) * PP + kwbase + quad * 8);

    for (int t = 0; t < numTiles; ++t) {
        const int tn  = (t + 1 < numTiles) ? (t + 1) : t;
        const int kwn = kwbase + tn * 64;

        // ---- issue ALL next-tile loads before any current-tile use ----
        const short8 kf0n = *(const short8*)(kB + (size_t)(kwn + col) * 8 + quad * 8);
        const short8 kf1n = *(const short8*)(kB + (size_t)(kwn + 16 + col) * 8 + quad * 8);
        short8 vfn[4];
#pragma unroll
        for (int cb = 0; cb < 4; ++cb)
            vfn[cb] = *(const short8*)(vB + ((size_t)(cb * 16 + col)) * PP + kwn + quad * 8);

        // ---- compute on current-tile fragments ----
#pragma unroll
        for (int qh = 0; qh < 4; ++qh) {
            const floatx4 E0 = __builtin_amdgcn_mfma_f32_16x16x32_bf16(
                kf0c, qfragB[qh], (floatx4){0.f, 0.f, 0.f, 0.f}, 0, 0, 0);
            const floatx4 E1 = __builtin_amdgcn_mfma_f32_16x16x32_bf16(
                kf1c, qfragB[qh], (floatx4){0.f, 0.f, 0.f, 0.f}, 0, 0, 0);

            // Schraudolph bf16 P, packed pairs (slots quad*8 + 0..7)
            intx4 pi;
            pi.x = (int)exp2_pk_bf16(E0[0], E0[1]);
            pi.y = (int)exp2_pk_bf16(E0[2], E0[3]);
            pi.z = (int)exp2_pk_bf16(E1[0], E1[1]);
            pi.w = (int)exp2_pk_bf16(E1[2], E1[3]);
            const short8 pf = __builtin_bit_cast(short8, pi);

            accLh[qh] = __builtin_amdgcn_mfma_f32_16x16x32_bf16(vones, pf, accLh[qh], 0, 0, 0);
#pragma unroll
            for (int cb = 0; cb < 4; ++cb)
                acc[qh][cb] = __builtin_amdgcn_mfma_f32_16x16x32_bf16(
                    vfc[cb], pf, acc[qh][cb], 0, 0, 0);
        }

        kf0c = kf0n;
        kf1c = kf1n;
#pragma unroll
        for (int cb = 0; cb < 4; ++cb) vfc[cb] = vfn[cb];
    }

    // ---- merge the two waves' key-halves via LDS; wave 0 stores ----
    if (wid == 1) {
#pragma unroll
        for (int qh = 0; qh < 4; ++qh)
#pragma unroll
            for (int cb = 0; cb < 4; ++cb)
#pragma unroll
                for (int r = 0; r < 4; ++r)
                    smerge[(cb * 16 + quad * 4 + r) * 64 + qh * 16 + col] = acc[qh][cb][r];
        if (quad == 0)
#pragma unroll
            for (int qh = 0; qh < 4; ++qh)
                slsum[qh * 16 + col] = accLh[qh][0];
    }
    __syncthreads();
    if (wid == 0) {
        ushort* ab = accp + ((size_t)g * BB + b) * CC * PP;
#pragma unroll
        for (int qh = 0; qh < 4; ++qh)
#pragma unroll
            for (int cb = 0; cb < 4; ++cb)
#pragma unroll
                for (int r = 0; r < 4; ++r) {
                    const int c = cb * 16 + quad * 4 + r;
                    const float v = acc[qh][cb][r] + smerge[c * 64 + qh * 16 + col];
                    ab[(size_t)c * PP + q0 + qh * 16 + col] = f2bf(v);
                }
        if (quad == 0) {
            float* lb = lsump + ((size_t)g * BB + b) * PP + q0;
#pragma unroll
            for (int qh = 0; qh < 4; ++qh)
                lb[qh * 16 + col] = accLh[qh][0] + slsum[qh * 16 + col];
        }
    }
}

// ---------------------------------------------------------------------------
// Kernel 3: combine G partials, normalize, + gamma*attn + x. 576 x 256,
// 8 consecutive pixels per thread (layouts already [b][c][p]-major).
// ---------------------------------------------------------------------------
__global__ __launch_bounds__(256)
void combine(const ushort* __restrict__ accp, const float* __restrict__ lsump,
             const float* __restrict__ x, const float* __restrict__ gamma,
             float* __restrict__ out, int G)
{
    const size_t i8 = ((size_t)blockIdx.x * 256 + threadIdx.x) * 8;
    const int b = (int)(i8 / ((size_t)CC * PP));
    const int p = (int)(i8 % PP);
    const float gm = gamma[0];

    float asum[8] = {}, lst[8] = {};
    for (int g = 0; g < G; ++g) {
        const uint4 av = *(const uint4*)(accp + (size_t)g * (BB * CC * PP) + i8);
        const unsigned int u[4] = {av.x, av.y, av.z, av.w};
#pragma unroll
        for (int k = 0; k < 4; ++k) {
            asum[2 * k]     += __uint_as_float(u[k] << 16);
            asum[2 * k + 1] += __uint_as_float(u[k] & 0xffff0000u);
        }
        const float* lp = lsump + ((size_t)g * BB + b) * PP + p;
        const float4 l0 = *(const float4*)lp;
        const float4 l1 = *(const float4*)(lp + 4);
        lst[0] += l0.x; lst[1] += l0.y; lst[2] += l0.z; lst[3] += l0.w;
        lst[4] += l1.x; lst[5] += l1.y; lst[6] += l1.z; lst[7] += l1.w;
    }

    const float4 x0 = *(const float4*)(x + i8);
    const float4 x1 = *(const float4*)(x + i8 + 4);
    float o[8] = {x0.x, x0.y, x0.z, x0.w, x1.x, x1.y, x1.z, x1.w};
#pragma unroll
    for (int j = 0; j < 8; ++j)
        o[j] = fmaf(asum[j], gm / fmaxf(lst[j], 1e-30f), o[j]);
    *(float4*)(out + i8)     = make_float4(o[0], o[1], o[2], o[3]);
    *(float4*)(out + i8 + 4) = make_float4(o[4], o[5], o[6], o[7]);
}

// ---------------------------------------------------------------------------
extern "C" void kernel_launch(void* const* d_in, const int* in_sizes, int n_in,
                              void* d_out, int out_size, void* d_ws, size_t ws_size,
                              hipStream_t stream)
{
    const float* x     = (const float*)d_in[0];
    const float* Wq    = (const float*)d_in[1];
    const float* bq    = (const float*)d_in[2];
    const float* Wk    = (const float*)d_in[3];
    const float* bk    = (const float*)d_in[4];
    const float* Wv    = (const float*)d_in[5];
    const float* bv    = (const float*)d_in[6];
    const float* gamma = (const float*)d_in[7];
    float* out = (float*)d_out;

    // ws: qbuf | kbuf | vfw (bf16) | accp (bf16, G slots) | lsump (f32)
    const size_t nQK  = (size_t)BB * PP * 8;        // elems
    const size_t nV   = (size_t)BB * CC * PP;
    const size_t base = 2 * nQK * 2 + nV * 2;       // bytes
    const size_t perG = nV * 2 + (size_t)BB * PP * 4;
    const int G = (ws_size >= base + 8 * perG) ? 8
                : (ws_size >= base + 6 * perG) ? 6
                : (ws_size >= base + 4 * perG) ? 4 : 2;
    const int keysPerG = PP / G;
    const int numTiles = keysPerG / 64;

    ushort* qbuf = (ushort*)d_ws;
    ushort* kbuf = qbuf + nQK;
    ushort* vfw  = kbuf + nQK;
    ushort* accp = vfw + nV;
    float* lsump = (float*)(accp + (size_t)G * nV);

    proj3<<<dim3(BB * 2 * QTILES), dim3(256), 0, stream>>>(
        x, Wq, bq, Wk, bk, Wv, bv, qbuf, kbuf, vfw);
    attn7<<<dim3(G * BB * QTILES), dim3(128), 0, stream>>>(
        qbuf, kbuf, vfw, accp, lsump, keysPerG, numTiles);
    combine<<<dim3(576), dim3(256), 0, stream>>>(
        accp, lsump, x, gamma, out, G);
}